// Round 5
// baseline (347.463 us; speedup 1.0000x reference)
//
#include <hip/hip_runtime.h>
#include <math.h>

#define SEQ   2048
#define DH    64
#define NBH   24
#define NCH   (SEQ / 128)     // 16 chunks of 128 k-cols
// scale * log2(e): softmax in exp2 domain
#define QSCALE 0.18033688011112042f

typedef __attribute__((ext_vector_type(8))) short short8;
typedef __attribute__((ext_vector_type(4))) float f32x4;
typedef __attribute__((ext_vector_type(4))) int   int4v;

#define MFMA(a, b, c) __builtin_amdgcn_mfma_f32_16x16x32_bf16((a), (b), (c), 0, 0, 0)

__device__ __forceinline__ unsigned bf16u(float f) {   // RNE-rounded, result in high 16
    union { float f; unsigned u; } x; x.f = f;
    return x.u + 0x7fffu + ((x.u >> 16) & 1u);
}
__device__ __forceinline__ short bf16rne(float f) { return (short)(bf16u(f) >> 16); }
__device__ __forceinline__ unsigned pack_bf162(float lo, float hi) {
    return (bf16u(lo) >> 16) | (bf16u(hi) & 0xffff0000u);
}

// ---- fused pre-pass: Q(+scale),K fp32->bf16 row-major; V -> V^T bf16 ----
__global__ __launch_bounds__(256)
void cvt_all(const float* __restrict__ q, const float* __restrict__ k,
             const float* __restrict__ v,
             short* __restrict__ qb, short* __restrict__ kb,
             short* __restrict__ vt)
{
    __shared__ float tile[64][65];
    const int t  = threadIdx.x;
    const int bh = blockIdx.x;
    const int s0 = blockIdx.y * 64;
    const size_t base = ((size_t)bh * SEQ + s0) * DH;

    #pragma unroll
    for (int i = 0; i < 4; ++i) {
        const int idx = i * 256 + t;
        float4 a = ((const float4*)(q + base))[idx];
        ((int2*)(qb + base))[idx] = make_int2(
            (int)pack_bf162(a.x * QSCALE, a.y * QSCALE),
            (int)pack_bf162(a.z * QSCALE, a.w * QSCALE));
        float4 b = ((const float4*)(k + base))[idx];
        ((int2*)(kb + base))[idx] = make_int2(
            (int)pack_bf162(b.x, b.y), (int)pack_bf162(b.z, b.w));
    }

    {
        const int sl = t >> 2, cg = (t & 3) * 16;
        const float* src = v + base + (size_t)sl * DH + cg;
        #pragma unroll
        for (int i = 0; i < 4; ++i)
            *(float4*)(&tile[sl][cg + 4 * i]) = ((const float4*)src)[i];
    }
    __syncthreads();
    {
        const int dl = t >> 2, sg = (t & 3) * 16;
        float f[16];
        #pragma unroll
        for (int j = 0; j < 16; ++j) f[j] = tile[sg + j][dl];
        short8 r0, r1;
        #pragma unroll
        for (int j = 0; j < 4; ++j) {
            ((int*)&r0)[j] = (int)pack_bf162(f[2 * j],     f[2 * j + 1]);
            ((int*)&r1)[j] = (int)pack_bf162(f[8 + 2 * j], f[9 + 2 * j]);
        }
        short* dst = vt + (size_t)bh * DH * SEQ + (size_t)dl * SEQ + s0 + sg;
        *(short8*)(dst)     = r0;
        *(short8*)(dst + 8) = r1;
    }
}

// ---- main: split-K flash attention, software-pipelined chunk loop ----
// Per iter: softmax(c) -> W (exp fused with bf16 pack); then a fused i-loop
// interleaves [P-transform + PV-MFMA of chunk kc] with [K loads + S-MFMA of
// chunk kc+1] so VMEM latency hides behind the MFMA/shuffle streams.
__global__ __launch_bounds__(256, 4)
void attn_fwd(const short* __restrict__ qb, const short* __restrict__ kb,
              const short* __restrict__ vt, float* __restrict__ og)
{
    __shared__ float lds_o[2][64][16];
    __shared__ float lds_m[2][16];
    __shared__ float lds_l[2][16];

    const int lane  = threadIdx.x & 63;
    const int wave  = threadIdx.x >> 6;
    const int qgrp  = wave >> 1;
    const int khalf = wave & 1;
    const int quad  = lane >> 4;
    const int l16   = lane & 15;
    const int bh    = blockIdx.x;
    const int q0    = blockIdx.y * 32 + qgrp * 16;

    const short* qrow  = qb + ((size_t)(bh * SEQ + q0 + l16)) * DH + quad * 8;
    const short* kbase = kb + (size_t)bh * SEQ * DH;
    const short* vbase = vt + (size_t)bh * DH * SEQ;

    const short8 bq0 = *(const short8*)(qrow);        // Q^T B-frags d 0..31
    const short8 bq1 = *(const short8*)(qrow + 32);   //             d 32..63

    f32x4 o[4];
    #pragma unroll
    for (int dt = 0; dt < 4; ++dt) o[dt] = (f32x4){0.f, 0.f, 0.f, 0.f};
    float m_i = -INFINITY, l_i = 0.f;

    const unsigned psel  = (quad < 2) ? 0x05040100u : 0x07060302u;
    const int      srcLo = l16 + ((quad & 1) << 5);
    const int      srcHi = srcLo + 16;

    const size_t klane = (size_t)l16 * DH + quad * 8;   // per-lane K offset
    const size_t vlane = (size_t)l16 * SEQ + quad * 8;  // per-lane V^T offset

    // ---- prologue: S^T of first chunk
    f32x4 c[8];
    {
        const int k0 = khalf * 8 * 128;
        #pragma unroll
        for (int mt = 0; mt < 8; ++mt) {
            const short* krow = kbase + (size_t)(k0 + mt * 16) * DH + klane;
            short8 ka0 = *(const short8*)(krow);
            short8 ka1 = *(const short8*)(krow + 32);
            f32x4 z = (f32x4){0.f, 0.f, 0.f, 0.f};
            z = MFMA(ka0, bq0, z);
            z = MFMA(ka1, bq1, z);
            c[mt] = z;
        }
    }

    #pragma unroll 1
    for (int iter = 0; iter < 8; ++iter) {
        const int k0  = (khalf * 8 + iter) * 128;
        const int k0n = k0 + 128;
        const bool more = (iter < 7);

        // ---- softmax: pairwise max tree, exp2 fused with bf16 pack
        float tm[4];
        #pragma unroll
        for (int e = 0; e < 4; ++e) {
            float a = fmaxf(fmaxf(c[0][e], c[1][e]), fmaxf(c[2][e], c[3][e]));
            float b = fmaxf(fmaxf(c[4][e], c[5][e]), fmaxf(c[6][e], c[7][e]));
            tm[e] = fmaxf(a, b);
        }
        float vmax = fmaxf(fmaxf(tm[0], tm[1]), fmaxf(tm[2], tm[3]));
        vmax = fmaxf(vmax, m_i);
        vmax = fmaxf(vmax, __shfl_xor(vmax, 16, 64));
        vmax = fmaxf(vmax, __shfl_xor(vmax, 32, 64));
        const float alpha = __builtin_amdgcn_exp2f(m_i - vmax);
        m_i = vmax;

        int W[16];
        float rs0 = 0.f, rs1 = 0.f;
        #pragma unroll
        for (int i2 = 0; i2 < 4; ++i2)
            #pragma unroll
            for (int r = 0; r < 4; ++r) {
                float p0 = __builtin_amdgcn_exp2f(c[2 * i2][r]     - m_i);
                float p1 = __builtin_amdgcn_exp2f(c[2 * i2 + 1][r] - m_i);
                rs0 += p0; rs1 += p1;
                W[i2 * 4 + r] = (int)pack_bf162(p0, p1);
            }
        float rs = rs0 + rs1;
        rs += __shfl_xor(rs, 16, 64);
        rs += __shfl_xor(rs, 32, 64);
        l_i = l_i * alpha + rs;
        #pragma unroll
        for (int dt = 0; dt < 4; ++dt)
            #pragma unroll
            for (int r = 0; r < 4; ++r) o[dt][r] *= alpha;

        // ---- fused: [transform + PV of kc] interleaved with [S-MFMA of kc+1]
        f32x4 cn[8];
        #pragma unroll
        for (int i = 0; i < 4; ++i) {
            int sA[4], sB[4];
            #pragma unroll
            for (int r = 0; r < 4; ++r) {
                int w = W[i * 4 + r];
                sA[r] = __shfl(w, srcLo, 64);
                sB[r] = __shfl(w, srcHi, 64);
            }
            int4v pw;
            pw[0] = (int)__builtin_amdgcn_perm((unsigned)sA[1], (unsigned)sA[0], psel);
            pw[1] = (int)__builtin_amdgcn_perm((unsigned)sA[3], (unsigned)sA[2], psel);
            pw[2] = (int)__builtin_amdgcn_perm((unsigned)sB[1], (unsigned)sB[0], psel);
            pw[3] = (int)__builtin_amdgcn_perm((unsigned)sB[3], (unsigned)sB[2], psel);
            short8 pf = __builtin_bit_cast(short8, pw);

            #pragma unroll
            for (int dt = 0; dt < 4; ++dt) {
                const short* vrow = vbase + (size_t)(dt * 16) * SEQ + vlane
                                  + k0 + i * 32;
                short8 av = *(const short8*)(vrow);
                o[dt] = MFMA(av, pf, o[dt]);
            }

            if (more) {
                #pragma unroll
                for (int h = 0; h < 2; ++h) {
                    const int mt = 2 * i + h;
                    const short* krow = kbase + (size_t)(k0n + mt * 16) * DH + klane;
                    short8 ka0 = *(const short8*)(krow);
                    short8 ka1 = *(const short8*)(krow + 32);
                    f32x4 z = (f32x4){0.f, 0.f, 0.f, 0.f};
                    z = MFMA(ka0, bq0, z);
                    z = MFMA(ka1, bq1, z);
                    cn[mt] = z;
                }
            }
        }
        if (more) {
            #pragma unroll
            for (int mt = 0; mt < 8; ++mt) c[mt] = cn[mt];
        }
    }

    // ---- cross-wave flash merge (khalf 1 -> LDS, khalf 0 combines+stores)
    if (khalf == 1) {
        #pragma unroll
        for (int dt = 0; dt < 4; ++dt)
            #pragma unroll
            for (int r = 0; r < 4; ++r)
                lds_o[qgrp][lane][dt * 4 + r] = o[dt][r];
        if (quad == 0) { lds_m[qgrp][l16] = m_i; lds_l[qgrp][l16] = l_i; }
    }
    __syncthreads();
    if (khalf == 0) {
        const float m2 = lds_m[qgrp][l16];
        const float l2 = lds_l[qgrp][l16];
        const float m  = fmaxf(m_i, m2);
        const float a1 = __builtin_amdgcn_exp2f(m_i - m);
        const float a2 = __builtin_amdgcn_exp2f(m2 - m);
        const float linv = 1.0f / (l_i * a1 + l2 * a2);
        float* orow = og + ((size_t)(bh * SEQ + q0 + l16)) * DH;
        #pragma unroll
        for (int dt = 0; dt < 4; ++dt) {
            f32x4 st;
            #pragma unroll
            for (int r = 0; r < 4; ++r)
                st[r] = (o[dt][r] * a1 + lds_o[qgrp][lane][dt * 4 + r] * a2) * linv;
            *(f32x4*)(orow + dt * 16 + quad * 4) = st;
        }
    }
}

extern "C" void kernel_launch(void* const* d_in, const int* in_sizes, int n_in,
                              void* d_out, int out_size, void* d_ws, size_t ws_size,
                              hipStream_t stream)
{
    const float* q = (const float*)d_in[0];
    const float* k = (const float*)d_in[1];
    const float* v = (const float*)d_in[2];
    float* o = (float*)d_out;

    const size_t nelem = (size_t)NBH * SEQ * DH;
    short* qb  = (short*)d_ws;
    short* kbp = qb + nelem;
    short* vtp = kbp + nelem;   // 18.9 MB total

    cvt_all<<<dim3(NBH, SEQ / 64), 256, 0, stream>>>(q, k, v, qb, kbp, vtp);
    attn_fwd<<<dim3(NBH, SEQ / 32), 256, 0, stream>>>(qb, kbp, vtp, o);
}

// Round 6
// 174.462 us; speedup vs baseline: 1.9916x; 1.9916x over previous
//
#include <hip/hip_runtime.h>
#include <math.h>

#define SEQ   2048
#define DH    64
#define NBH   24
// scale * log2(e): softmax in exp2 domain
#define QSCALE 0.18033688011112042f

typedef __attribute__((ext_vector_type(8))) short short8;
typedef __attribute__((ext_vector_type(4))) float f32x4;
typedef __attribute__((ext_vector_type(4))) int   int4v;

#define MFMA(a, b, c) __builtin_amdgcn_mfma_f32_16x16x32_bf16((a), (b), (c), 0, 0, 0)

__device__ __forceinline__ unsigned bf16u(float f) {   // RNE-rounded, result in high 16
    union { float f; unsigned u; } x; x.f = f;
    return x.u + 0x7fffu + ((x.u >> 16) & 1u);
}
__device__ __forceinline__ unsigned pack_bf162(float lo, float hi) {
    return (bf16u(lo) >> 16) | (bf16u(hi) & 0xffff0000u);
}

// ---- fused pre-pass: Q(+scale),K fp32->bf16 row-major; V -> V^T bf16 ----
__global__ __launch_bounds__(256)
void cvt_all(const float* __restrict__ q, const float* __restrict__ k,
             const float* __restrict__ v,
             short* __restrict__ qb, short* __restrict__ kb,
             short* __restrict__ vt)
{
    __shared__ float tile[64][65];
    const int t  = threadIdx.x;
    const int bh = blockIdx.x;
    const int s0 = blockIdx.y * 64;
    const size_t base = ((size_t)bh * SEQ + s0) * DH;

    #pragma unroll
    for (int i = 0; i < 4; ++i) {
        const int idx = i * 256 + t;
        float4 a = ((const float4*)(q + base))[idx];
        ((int2*)(qb + base))[idx] = make_int2(
            (int)pack_bf162(a.x * QSCALE, a.y * QSCALE),
            (int)pack_bf162(a.z * QSCALE, a.w * QSCALE));
        float4 b = ((const float4*)(k + base))[idx];
        ((int2*)(kb + base))[idx] = make_int2(
            (int)pack_bf162(b.x, b.y), (int)pack_bf162(b.z, b.w));
    }

    {
        const int sl = t >> 2, cg = (t & 3) * 16;
        const float* src = v + base + (size_t)sl * DH + cg;
        #pragma unroll
        for (int i = 0; i < 4; ++i)
            *(float4*)(&tile[sl][cg + 4 * i]) = ((const float4*)src)[i];
    }
    __syncthreads();
    {
        const int dl = t >> 2, sg = (t & 3) * 16;
        float f[16];
        #pragma unroll
        for (int j = 0; j < 16; ++j) f[j] = tile[sg + j][dl];
        short8 r0, r1;
        #pragma unroll
        for (int j = 0; j < 4; ++j) {
            ((int*)&r0)[j] = (int)pack_bf162(f[2 * j],     f[2 * j + 1]);
            ((int*)&r1)[j] = (int)pack_bf162(f[8 + 2 * j], f[9 + 2 * j]);
        }
        short* dst = vt + (size_t)bh * DH * SEQ + (size_t)dl * SEQ + s0 + sg;
        *(short8*)(dst)     = r0;
        *(short8*)(dst + 8) = r1;
    }
}

// ---- main: split-K flash, 32 q-rows/wave, 64-col chunks, K reg-prefetch ----
// Block = 4 waves = (qgrp, khalf); wave covers q-rows [q0, q0+32) as two
// 16-row MFMA subtiles. Each K/V frag feeds 2 MFMAs (vs 1 in R2-R4):
// halves VMEM instrs per q-row, which R4's counters say is the bottleneck.
// launch_bounds(256,3): residency is grid-limited at 12 waves/CU (R3: more
// occupancy didn't help), so allow ~170 regs -> no spill (R5's failure).
__global__ __launch_bounds__(256, 3)
void attn_fwd(const short* __restrict__ qb, const short* __restrict__ kb,
              const short* __restrict__ vt, float* __restrict__ og)
{
    __shared__ float lds_o[2][2][64][16];
    __shared__ float lds_m[2][2][16];
    __shared__ float lds_l[2][2][16];

    const int lane  = threadIdx.x & 63;
    const int wave  = threadIdx.x >> 6;
    const int qgrp  = wave >> 1;
    const int khalf = wave & 1;
    const int quad  = lane >> 4;
    const int l16   = lane & 15;
    const int bh    = blockIdx.x;
    const int q0    = blockIdx.y * 64 + qgrp * 32;

    const short* kbase = kb + (size_t)bh * SEQ * DH;
    const short* vbase = vt + (size_t)bh * DH * SEQ;

    short8 bq[2][2];
    #pragma unroll
    for (int qs = 0; qs < 2; ++qs) {
        const short* qrow = qb + ((size_t)(bh * SEQ + q0 + qs * 16 + l16)) * DH + quad * 8;
        bq[qs][0] = *(const short8*)(qrow);
        bq[qs][1] = *(const short8*)(qrow + 32);
    }

    f32x4 o[2][4];
    float m_i[2], l_i[2];
    #pragma unroll
    for (int qs = 0; qs < 2; ++qs) {
        m_i[qs] = -INFINITY; l_i[qs] = 0.f;
        #pragma unroll
        for (int dt = 0; dt < 4; ++dt) o[qs][dt] = (f32x4){0.f, 0.f, 0.f, 0.f};
    }

    const unsigned psel  = (quad < 2) ? 0x05040100u : 0x07060302u;
    const int      srcLo = l16 + ((quad & 1) << 5);
    const int      srcHi = srcLo + 16;

    const size_t klane = (size_t)l16 * DH + quad * 8;
    const size_t vlane = (size_t)l16 * SEQ + quad * 8;

    // prologue: K frags of first chunk (4 mt x 2 d-halves)
    short8 ka[8];
    int k0 = khalf * (SEQ / 2);
    #pragma unroll
    for (int mt = 0; mt < 4; ++mt) {
        const short* krow = kbase + (size_t)(k0 + mt * 16) * DH + klane;
        ka[2 * mt]     = *(const short8*)(krow);
        ka[2 * mt + 1] = *(const short8*)(krow + 32);
    }

    #pragma unroll 1
    for (int iter = 0; iter < 16; ++iter, k0 += 64) {
        // ---- S^T = K @ Q^T: each K-frag pair feeds both q-subtiles
        f32x4 c[2][4];
        #pragma unroll
        for (int mt = 0; mt < 4; ++mt)
            #pragma unroll
            for (int qs = 0; qs < 2; ++qs) {
                f32x4 z = (f32x4){0.f, 0.f, 0.f, 0.f};
                z = MFMA(ka[2 * mt],     bq[qs][0], z);
                z = MFMA(ka[2 * mt + 1], bq[qs][1], z);
                c[qs][mt] = z;
            }

        // ---- prefetch next chunk's K frags (in flight through softmax+PV)
        if (iter < 15) {
            const int k0n = k0 + 64;
            #pragma unroll
            for (int mt = 0; mt < 4; ++mt) {
                const short* krow = kbase + (size_t)(k0n + mt * 16) * DH + klane;
                ka[2 * mt]     = *(const short8*)(krow);
                ka[2 * mt + 1] = *(const short8*)(krow + 32);
            }
        }

        // ---- online softmax per q-subtile; exp2 fused with bf16 pack
        int W[2][8];
        #pragma unroll
        for (int qs = 0; qs < 2; ++qs) {
            float tm[4];
            #pragma unroll
            for (int e = 0; e < 4; ++e)
                tm[e] = fmaxf(fmaxf(c[qs][0][e], c[qs][1][e]),
                              fmaxf(c[qs][2][e], c[qs][3][e]));
            float vmax = fmaxf(fmaxf(tm[0], tm[1]), fmaxf(tm[2], tm[3]));
            vmax = fmaxf(vmax, m_i[qs]);
            vmax = fmaxf(vmax, __shfl_xor(vmax, 16, 64));
            vmax = fmaxf(vmax, __shfl_xor(vmax, 32, 64));
            const float alpha = __builtin_amdgcn_exp2f(m_i[qs] - vmax);
            m_i[qs] = vmax;

            float rs0 = 0.f, rs1 = 0.f;
            #pragma unroll
            for (int i2 = 0; i2 < 2; ++i2)
                #pragma unroll
                for (int r = 0; r < 4; ++r) {
                    float p0 = __builtin_amdgcn_exp2f(c[qs][2 * i2][r]     - vmax);
                    float p1 = __builtin_amdgcn_exp2f(c[qs][2 * i2 + 1][r] - vmax);
                    rs0 += p0; rs1 += p1;
                    W[qs][i2 * 4 + r] = (int)pack_bf162(p0, p1);
                }
            float rs = rs0 + rs1;
            rs += __shfl_xor(rs, 16, 64);
            rs += __shfl_xor(rs, 32, 64);
            l_i[qs] = l_i[qs] * alpha + rs;
            #pragma unroll
            for (int dt = 0; dt < 4; ++dt)
                #pragma unroll
                for (int r = 0; r < 4; ++r) o[qs][dt][r] *= alpha;
        }

        // ---- PV: V A-frags shared by both q-subtiles
        #pragma unroll
        for (int kch = 0; kch < 2; ++kch) {
            short8 av[4];
            #pragma unroll
            for (int dt = 0; dt < 4; ++dt) {
                const short* vrow = vbase + (size_t)(dt * 16) * SEQ + vlane
                                  + k0 + kch * 32;
                av[dt] = *(const short8*)(vrow);
            }
            #pragma unroll
            for (int qs = 0; qs < 2; ++qs) {
                int sA[4], sB[4];
                #pragma unroll
                for (int r = 0; r < 4; ++r) {
                    int w = W[qs][kch * 4 + r];
                    sA[r] = __shfl(w, srcLo, 64);
                    sB[r] = __shfl(w, srcHi, 64);
                }
                int4v pw;
                pw[0] = (int)__builtin_amdgcn_perm((unsigned)sA[1], (unsigned)sA[0], psel);
                pw[1] = (int)__builtin_amdgcn_perm((unsigned)sA[3], (unsigned)sA[2], psel);
                pw[2] = (int)__builtin_amdgcn_perm((unsigned)sB[1], (unsigned)sB[0], psel);
                pw[3] = (int)__builtin_amdgcn_perm((unsigned)sB[3], (unsigned)sB[2], psel);
                short8 pf = __builtin_bit_cast(short8, pw);
                #pragma unroll
                for (int dt = 0; dt < 4; ++dt)
                    o[qs][dt] = MFMA(av[dt], pf, o[qs][dt]);
            }
        }
    }

    // ---- cross-wave flash merge (khalf 1 -> LDS, khalf 0 combines+stores)
    if (khalf == 1) {
        #pragma unroll
        for (int qs = 0; qs < 2; ++qs) {
            #pragma unroll
            for (int dt = 0; dt < 4; ++dt)
                #pragma unroll
                for (int r = 0; r < 4; ++r)
                    lds_o[qgrp][qs][lane][dt * 4 + r] = o[qs][dt][r];
            if (quad == 0) {
                lds_m[qgrp][qs][l16] = m_i[qs];
                lds_l[qgrp][qs][l16] = l_i[qs];
            }
        }
    }
    __syncthreads();
    if (khalf == 0) {
        #pragma unroll
        for (int qs = 0; qs < 2; ++qs) {
            const float m2 = lds_m[qgrp][qs][l16];
            const float l2 = lds_l[qgrp][qs][l16];
            const float m  = fmaxf(m_i[qs], m2);
            const float a1 = __builtin_amdgcn_exp2f(m_i[qs] - m);
            const float a2 = __builtin_amdgcn_exp2f(m2 - m);
            const float linv = 1.0f / (l_i[qs] * a1 + l2 * a2);
            float* orow = og + ((size_t)(bh * SEQ + q0 + qs * 16 + l16)) * DH;
            #pragma unroll
            for (int dt = 0; dt < 4; ++dt) {
                f32x4 st;
                #pragma unroll
                for (int r = 0; r < 4; ++r)
                    st[r] = (o[qs][dt][r] * a1
                           + lds_o[qgrp][qs][lane][dt * 4 + r] * a2) * linv;
                *(f32x4*)(orow + dt * 16 + quad * 4) = st;
            }
        }
    }
}

extern "C" void kernel_launch(void* const* d_in, const int* in_sizes, int n_in,
                              void* d_out, int out_size, void* d_ws, size_t ws_size,
                              hipStream_t stream)
{
    const float* q = (const float*)d_in[0];
    const float* k = (const float*)d_in[1];
    const float* v = (const float*)d_in[2];
    float* o = (float*)d_out;

    const size_t nelem = (size_t)NBH * SEQ * DH;
    short* qb  = (short*)d_ws;
    short* kbp = qb + nelem;
    short* vtp = kbp + nelem;   // 18.9 MB total

    cvt_all<<<dim3(NBH, SEQ / 64), 256, 0, stream>>>(q, k, v, qb, kbp, vtp);
    attn_fwd<<<dim3(NBH, SEQ / 64), 256, 0, stream>>>(qb, kbp, vtp, o);
}